// Round 8
// baseline (206.668 us; speedup 1.0000x reference)
//
#include <hip/hip_runtime.h>

// APMLSparse: B=4, N=M=4096, D=3.
// loss = sum_rows sum_{kept j} p_ij * d_ij, p = softmax_j(-d_i),
// kept = descending-p prefix until cumulative mass >= P_MIN = 0.8.
//
// R8: wave-per-row, p-space selection (p = exp(-d), unnormalized).
//  - p stored as packed f32x2[32]; hot scans use VOP3P (v_pk_max/v_pk_add)
//    -> ~2 VALU/elem probes, and VOP3P forces p into real VGPRs (no AGPR
//    round-trips, unlike R5-R7 where VGPR_Count=44 betrayed AGPR storage).
//  - Probe mass via identity: G(s) = sum max(p,s) - s*(4096 - C), count C
//    from v_cmp+ballot (SALU popc). Exact re-base pass after Phase A
//    recomputes G(sh) with masked sums so the compact-set walk + tie logic
//    (bit-proven in R6/R7, absmax 0.0) sees exact masses.
//  - y loaded as float3 (dwordx3): 64 loads/row instead of 192.

#define MCOLS 4096
#define KPT2  32            // 4096 / 64 lanes / 2 (packed pairs)
#define WPB   4             // waves per block
#define P_MIN 0.8f

typedef __attribute__((ext_vector_type(2))) float f32x2;

__device__ __forceinline__ f32x2 pkmax(f32x2 a, f32x2 b) {
#if __has_builtin(__builtin_elementwise_max)
    return __builtin_elementwise_max(a, b);
#else
    f32x2 r; r.x = fmaxf(a.x, b.x); r.y = fmaxf(a.y, b.y); return r;
#endif
}

// ---- DPP wave64 reductions (old=0 => inactive lanes contribute 0) ----
template <int CTRL, int RM, int BM, bool BC>
__device__ __forceinline__ float dpp_mov0(float x) {
    return __int_as_float(__builtin_amdgcn_update_dpp(
        0, __float_as_int(x), CTRL, RM, BM, BC));
}
__device__ __forceinline__ float dppSum(float v) {
    v += dpp_mov0<0x111, 0xF, 0xF, true >(v);   // row_shr:1
    v += dpp_mov0<0x112, 0xF, 0xF, true >(v);   // row_shr:2
    v += dpp_mov0<0x114, 0xF, 0xF, true >(v);   // row_shr:4
    v += dpp_mov0<0x118, 0xF, 0xF, true >(v);   // row_shr:8
    v += dpp_mov0<0x142, 0xA, 0xF, false>(v);   // row_bcast15 -> rows 1,3
    v += dpp_mov0<0x143, 0xC, 0xF, false>(v);   // row_bcast31 -> rows 2,3
    return __int_as_float(__builtin_amdgcn_readlane(__float_as_int(v), 63));
}
__device__ __forceinline__ float dppMax(float v) {   // nonneg inputs only
    v = fmaxf(v, dpp_mov0<0x111, 0xF, 0xF, true >(v));
    v = fmaxf(v, dpp_mov0<0x112, 0xF, 0xF, true >(v));
    v = fmaxf(v, dpp_mov0<0x114, 0xF, 0xF, true >(v));
    v = fmaxf(v, dpp_mov0<0x118, 0xF, 0xF, true >(v));
    v = fmaxf(v, dpp_mov0<0x142, 0xA, 0xF, false>(v));
    v = fmaxf(v, dpp_mov0<0x143, 0xC, 0xF, false>(v));
    return __int_as_float(__builtin_amdgcn_readlane(__float_as_int(v), 63));
}

__global__ __launch_bounds__(WPB * 64) void apml_row_wave(
        const float* __restrict__ x, const float* __restrict__ y,
        float* __restrict__ out) {
    __shared__ __align__(16) float scomp[WPB * 256];
    __shared__ float wacc[WPB];

    const int tid  = threadIdx.x;
    const int wid  = tid >> 6;
    const int lane = tid & 63;
    const int row  = blockIdx.x * WPB + wid;
    const int b    = row >> 12;                 // row / 4096

    const float x0 = x[row * 3 + 0];
    const float x1 = x[row * 3 + 1];
    const float x2 = x[row * 3 + 2];
    const float3* yb3 = (const float3*)(y + (size_t)b * MCOLS * 3);

    // ---- setup: p = exp(-d), packed pairs; Z and pmax via DPP ----
    f32x2 p2[KPT2];
    f32x2 z2 = {0.0f, 0.0f};
    f32x2 pm2 = {0.0f, 0.0f};
    #pragma unroll
    for (int k = 0; k < KPT2; ++k) {
        const int j0 = (2 * k) * 64 + lane;
        const int j1 = j0 + 64;
        const float3 a = yb3[j0];
        const float3 c = yb3[j1];
        f32x2 dx; dx.x = x0 - a.x; dx.y = x0 - c.x;
        f32x2 dy; dy.x = x1 - a.y; dy.y = x1 - c.y;
        f32x2 dz; dz.x = x2 - a.z; dz.y = x2 - c.z;
        f32x2 sq = dx * dx + dy * dy + dz * dz;
        sq = pkmax(sq, (f32x2){1e-12f, 1e-12f});        // EPS^2 clamp
        f32x2 pk;
        pk.x = __expf(-sqrtf(sq.x));
        pk.y = __expf(-sqrtf(sq.y));
        p2[k] = pk;
        z2 += pk;
        pm2 = pkmax(pm2, pk);
    }
    const float Z    = dppSum(z2.x + z2.y);
    const float pmax = dppMax(fmaxf(pm2.x, pm2.y));
    const float target = P_MIN * Z;
    const float pTop = __uint_as_float(__float_as_uint(pmax) + 1u);

    // ---- sampled warm-start: 5 probes on p2[0..1] (256 elements) ----
    float ssl = 0.0f, ssh = pTop;
    {
        float eGl = 16.0f * dppSum(p2[0].x + p2[0].y + p2[1].x + p2[1].y);
        float eGh = 0.0f;
        for (int it = 0; it < 5; ++it) {
            float s;
            if (it & 1) {
                s = 0.5f * (ssl + ssh);
            } else {
                const float den = fmaxf(eGl - eGh, 1e-30f);
                s = ssl + (ssh - ssl) * ((eGl - target) / den);
            }
            if (!(s > ssl && s < ssh)) s = 0.5f * (ssl + ssh);
            if (!(s > ssl && s < ssh)) break;
            float m = 0.0f;
            m += (p2[0].x >= s) ? p2[0].x : 0.0f;
            m += (p2[0].y >= s) ? p2[0].y : 0.0f;
            m += (p2[1].x >= s) ? p2[1].x : 0.0f;
            m += (p2[1].y >= s) ? p2[1].y : 0.0f;
            m = 16.0f * dppSum(m);
            if (m >= target) { ssl = s; eGl = m; }
            else             { ssh = s; eGh = m; }
        }
    }

    // ---- Phase A: packed probes (max-identity) until band <= 256 ----
    // Invariant: G(sl) >= target > G(sh), G(s) = mass of {p >= s}.
    float sl = 0.0f, sh = pTop;
    float Gl = Z,    Gh = 0.0f;
    int   Cl = MCOLS, Ch = 0;

    for (int it = 0; it < 12 && (Cl - Ch) > 256; ++it) {
        float s;
        if      (it == 0) s = ssl;
        else if (it == 1) s = ssh;
        else if (it & 1)  s = 0.5f * (sl + sh);
        else {
            const float den = fmaxf(Gl - Gh, 1e-30f);
            s = sl + (sh - sl) * ((Gl - target) / den);
        }
        if (!(s > sl && s < sh)) s = 0.5f * (sl + sh);
        if (!(s > sl && s < sh)) break;        // ulp-width bracket

        const f32x2 ss = {s, s};
        f32x2 acc = {0.0f, 0.0f};
        int c = 0;
        #pragma unroll
        for (int k = 0; k < KPT2; ++k) {
            acc += pkmax(p2[k], ss);           // v_pk_max + v_pk_add
            c += (int)__popcll(__ballot(p2[k].x >= s));
            c += (int)__popcll(__ballot(p2[k].y >= s));
        }
        const float F = dppSum(acc.x + acc.y);
        const float m = F - s * (float)(MCOLS - c);   // identity mass
        if (m >= target) { sl = s; Gl = m; Cl = c; }
        else             { sh = s; Gh = m; Ch = c; }
    }

    // ---- exact re-base: recompute G(sh) with masked sums (kills the
    //      cancellation error of the identity before the exact phases) ----
    {
        float gh = 0.0f;
        #pragma unroll
        for (int k = 0; k < KPT2; ++k) {
            gh += (p2[k].x >= sh) ? p2[k].x : 0.0f;
            gh += (p2[k].y >= sh) ? p2[k].y : 0.0f;
        }
        Gh = dppSum(gh);
    }

    // ---- Phase B: compact band [sl, sh) into 4 regs per lane ----
    int C = 0;
    #pragma unroll
    for (int k = 0; k < KPT2; ++k) {
        #pragma unroll
        for (int h = 0; h < 2; ++h) {
            const float pv = (h == 0) ? p2[k].x : p2[k].y;
            const bool band = (pv >= sl) && (pv < sh);
            const unsigned long long mk = __ballot(band);
            if (band) {
                const unsigned mlo = (unsigned)mk, mhi = (unsigned)(mk >> 32);
                const int within = __builtin_amdgcn_mbcnt_hi(
                                       mhi, __builtin_amdgcn_mbcnt_lo(mlo, 0));
                const int pos = C + within;
                if (pos < 256) scomp[wid * 256 + pos] = pv;
            }
            C += (int)__popcll(mk);
        }
    }
    __builtin_amdgcn_s_waitcnt(0);             // drain ds_writes (same wave)
    float cp[4];
    bool  cv[4];
    #pragma unroll
    for (int q = 0; q < 4; ++q) {
        const int idx = q * 64 + lane;
        cv[q] = (idx < C) && (idx < 256);
        cp[q] = cv[q] ? scomp[wid * 256 + idx] : 0.0f;
    }

    float pstar, mb = 0.0f;
    int   cnt = 1;
    bool  haveTie;

    if (C > 256) {
        // fallback (rare): keep everything >= sl (off by <=2 boundary elems)
        pstar = (sl > 0.0f) ? __uint_as_float(__float_as_uint(sl) - 1u) : 0.0f;
        haveTie = false;
    } else {
        // ---- Phase C1: cheap fine probes on the compact set ----
        float lo_s = sl, hi_s = sh, lo_G = Gl, hi_G = Gh;
        int   lo_C = Cl, hi_C = Ch;
        for (int it = 0; it < 10 && (lo_C - hi_C) > 2; ++it) {
            float s;
            if (it & 1) {
                s = 0.5f * (lo_s + hi_s);
            } else {
                const float den = fmaxf(lo_G - hi_G, 1e-30f);
                s = lo_s + (hi_s - lo_s) * ((lo_G - target) / den);
            }
            if (!(s > lo_s && s < hi_s)) s = 0.5f * (lo_s + hi_s);
            if (!(s > lo_s && s < hi_s)) break;

            float m = 0.0f;
            int   c = Ch;
            #pragma unroll
            for (int q = 0; q < 4; ++q) {
                const bool ge = cv[q] && (cp[q] >= s);
                m += ge ? cp[q] : 0.0f;
                c += (int)__popcll(__ballot(ge));
            }
            m = Gh + dppSum(m);
            if (m >= target) { lo_s = s; lo_G = m; lo_C = c; }
            else             { hi_s = s; hi_G = m; hi_C = c; }
        }

        // ---- Phase C2: exact distinct-value walk downward from hi_s ----
        float scur = hi_s, M = hi_G;
        bool ok = false;
        pstar = lo_s;
        for (int e = 0; e < 16; ++e) {
            float vl = 0.0f;
            #pragma unroll
            for (int q = 0; q < 4; ++q)
                vl = fmaxf(vl, (cv[q] && cp[q] < scur) ? cp[q] : 0.0f);
            const float v = dppMax(vl);
            if (!(v > 0.0f)) break;            // fp knife-edge; fallback
            int cvn = 0;
            #pragma unroll
            for (int q = 0; q < 4; ++q)
                cvn += (int)__popcll(__ballot(cv[q] && (cp[q] == v)));
            const float Mn = M + v * (float)cvn;  // exact: ties bit-identical
            if (Mn >= target) { pstar = v; mb = M; cnt = cvn; ok = true; break; }
            M = Mn; scur = v;
        }
        haveTie = ok;
        if (!ok) {
            pstar = (lo_s > 0.0f) ? __uint_as_float(__float_as_uint(lo_s) - 1u)
                                  : 0.0f;
        }
    }

    // ---- Phase D: spd = sum_{p > p*} p * (-log p) via select-to-1 ----
    float spd = 0.0f;
    #pragma unroll
    for (int k = 0; k < KPT2; ++k) {
        const float t0 = (p2[k].x > pstar) ? p2[k].x : 1.0f;   // log(1)=0
        const float t1 = (p2[k].y > pstar) ? p2[k].y : 1.0f;
        spd += t0 * (-__logf(t0));
        spd += t1 * (-__logf(t1));
    }
    spd = dppSum(spd);

    if (lane == 0) {
        float tie = 0.0f;
        if (haveTie) {
            const float R = (target - mb) / pstar;      // exclusive-csum rule
            int q = (int)ceilf(R);
            if (q < 1) q = 1;
            if (q > cnt) q = cnt;
            tie = (float)q * pstar * (-__logf(pstar));
        }
        wacc[wid] = (spd + tie) / Z;
    }
    __syncthreads();                     // all waves reach exactly once
    if (tid == 0) {
        atomicAdd(out, wacc[0] + wacc[1] + wacc[2] + wacc[3]);
    }
}

extern "C" void kernel_launch(void* const* d_in, const int* in_sizes, int n_in,
                              void* d_out, int out_size, void* d_ws, size_t ws_size,
                              hipStream_t stream) {
    const float* x = (const float*)d_in[0];   // [B, N, 3]
    const float* y = (const float*)d_in[1];   // [B, M, 3]
    float* out = (float*)d_out;               // scalar

    const int nrows = in_sizes[0] / 3;        // B * N
    const int nblocks = nrows / WPB;

    hipMemsetAsync(out, 0, sizeof(float), stream);   // capture-legal stream op
    apml_row_wave<<<nblocks, WPB * 64, 0, stream>>>(x, y, out);
}

// Round 9
// 188.314 us; speedup vs baseline: 1.0975x; 1.0975x over previous
//
#include <hip/hip_runtime.h>

// APMLSparse: B=4, N=M=4096, D=3.
// loss = sum_rows sum_{kept j} p_ij * d_ij, p = softmax_j(-d_i),
// kept = descending-p prefix until cumulative mass >= P_MIN = 0.8.
//
// R9: wave-per-row, p-space selection (p = exp(-d), unnormalized),
// scalar p[64] + DPP reductions (R7 structure — measured best).
// Full-array passes cut from ~6 to ~4:
//  - setup also accumulates spd_all = sum p*d (d live there, 1 fma);
//  - final pass ELIMINATED: spd_kept = spd_all - S_lo - S_band_le, where
//    S_lo (= sum_{p<sl} p*(-log p)) is fused into the compaction pass and
//    S_band_le is 8 logs on the compact registers;
//  - warm-start bracket widened 1x width each side + band capacity 512
//    (8 regs/lane) so Phase A usually ends right after its 2 seed probes.
// Exact probe/walk/tie machinery identical to R6/R7 (absmax 0.0).

#define MCOLS 4096
#define KPT   64            // 4096 / 64 lanes
#define WPB   4             // waves per block
#define P_MIN 0.8f
#define CAP   512           // band capacity (8 regs/lane)

// ---- DPP wave64 reductions (old=0 => shifted-in lanes contribute 0) ----
template <int CTRL, int RM, int BM, bool BC>
__device__ __forceinline__ float dpp_mov0(float x) {
    return __int_as_float(__builtin_amdgcn_update_dpp(
        0, __float_as_int(x), CTRL, RM, BM, BC));
}
__device__ __forceinline__ float dppSum(float v) {
    v += dpp_mov0<0x111, 0xF, 0xF, true >(v);   // row_shr:1
    v += dpp_mov0<0x112, 0xF, 0xF, true >(v);   // row_shr:2
    v += dpp_mov0<0x114, 0xF, 0xF, true >(v);   // row_shr:4
    v += dpp_mov0<0x118, 0xF, 0xF, true >(v);   // row_shr:8
    v += dpp_mov0<0x142, 0xA, 0xF, false>(v);   // row_bcast15 -> rows 1,3
    v += dpp_mov0<0x143, 0xC, 0xF, false>(v);   // row_bcast31 -> rows 2,3
    return __int_as_float(__builtin_amdgcn_readlane(__float_as_int(v), 63));
}
__device__ __forceinline__ float dppMax(float v) {   // nonneg inputs only
    v = fmaxf(v, dpp_mov0<0x111, 0xF, 0xF, true >(v));
    v = fmaxf(v, dpp_mov0<0x112, 0xF, 0xF, true >(v));
    v = fmaxf(v, dpp_mov0<0x114, 0xF, 0xF, true >(v));
    v = fmaxf(v, dpp_mov0<0x118, 0xF, 0xF, true >(v));
    v = fmaxf(v, dpp_mov0<0x142, 0xA, 0xF, false>(v));
    v = fmaxf(v, dpp_mov0<0x143, 0xC, 0xF, false>(v));
    return __int_as_float(__builtin_amdgcn_readlane(__float_as_int(v), 63));
}

__global__ __launch_bounds__(WPB * 64) void apml_row_wave(
        const float* __restrict__ x, const float* __restrict__ y,
        float* __restrict__ out) {
    __shared__ __align__(16) float scomp[WPB * CAP];
    __shared__ float wacc[WPB];

    const int tid  = threadIdx.x;
    const int wid  = tid >> 6;
    const int lane = tid & 63;
    const int row  = blockIdx.x * WPB + wid;
    const int b    = row >> 12;                 // row / 4096

    const float x0 = x[row * 3 + 0];
    const float x1 = x[row * 3 + 1];
    const float x2 = x[row * 3 + 2];
    const float* yb = y + (size_t)b * MCOLS * 3;

    // ---- setup: p = exp(-d); Z, pmax, and spd_all = sum p*d ----
    float p[KPT];
    float zl = 0.0f, pml = 0.0f, sal = 0.0f;
    #pragma unroll
    for (int k = 0; k < KPT; ++k) {
        const int j = k * 64 + lane;
        const float y0 = yb[j * 3 + 0];
        const float y1 = yb[j * 3 + 1];
        const float y2 = yb[j * 3 + 2];
        const float dx = x0 - y0, dy = x1 - y1, dz = x2 - y2;
        const float sq = fmaxf(dx * dx + dy * dy + dz * dz, 1e-12f); // EPS^2
        const float dd = sqrtf(sq);
        const float pk = __expf(-dd);
        p[k] = pk;
        zl  += pk;
        pml  = fmaxf(pml, pk);
        sal  = fmaf(pk, dd, sal);               // spd over ALL elements
    }
    const float Z       = dppSum(zl);
    const float pmax    = dppMax(pml);
    const float spd_all = dppSum(sal);
    const float target  = P_MIN * Z;
    const float pTop = __uint_as_float(__float_as_uint(pmax) + 1u);

    // ---- sampled warm-start: 4 probes on p[0..3] (256 elements) ----
    float ssl = 0.0f, ssh = pTop;
    {
        float eGl = 16.0f * dppSum(p[0] + p[1] + p[2] + p[3]);  // Ghat(0)
        float eGh = 0.0f;
        for (int it = 0; it < 4; ++it) {
            float s;
            if (it & 1) {
                s = 0.5f * (ssl + ssh);
            } else {
                const float den = fmaxf(eGl - eGh, 1e-30f);
                s = ssl + (ssh - ssl) * ((eGl - target) / den);
            }
            if (!(s > ssl && s < ssh)) s = 0.5f * (ssl + ssh);
            if (!(s > ssl && s < ssh)) break;
            float m = 0.0f;
            #pragma unroll
            for (int q = 0; q < 4; ++q) m += (p[q] >= s) ? p[q] : 0.0f;
            m = 16.0f * dppSum(m);
            if (m >= target) { ssl = s; eGl = m; }
            else             { ssh = s; eGh = m; }
        }
    }
    // widen sampled bracket by one width each side (sampling noise guard)
    const float wbw = ssh - ssl;
    const float seed_lo = fmaxf(ssl - wbw, 0.0f);
    const float seed_hi = fminf(ssh + wbw, pTop);

    // ---- Phase A: exact probes until band <= CAP ----
    // Invariant: G(sl) >= target > G(sh), G(s) = mass of {p >= s}.
    float sl = 0.0f, sh = pTop;
    float Gl = Z,    Gh = 0.0f;
    int   Cl = MCOLS, Ch = 0;

    for (int it = 0; it < 12 && (Cl - Ch) > CAP; ++it) {
        float s;
        if      (it == 0) s = seed_lo;
        else if (it == 1) s = seed_hi;
        else if (it & 1)  s = 0.5f * (sl + sh);
        else {
            const float den = fmaxf(Gl - Gh, 1e-30f);
            s = sl + (sh - sl) * ((Gl - target) / den);
        }
        if (!(s > sl && s < sh)) s = 0.5f * (sl + sh);
        if (!(s > sl && s < sh)) break;        // ulp-width bracket

        float m = 0.0f;
        int   c = 0;
        #pragma unroll
        for (int k = 0; k < KPT; ++k) {
            const bool ge = (p[k] >= s);
            m += ge ? p[k] : 0.0f;
            c += (int)__popcll(__ballot(ge));
        }
        m = dppSum(m);
        if (m >= target) { sl = s; Gl = m; Cl = c; }
        else             { sh = s; Gh = m; Ch = c; }
    }

    // ---- fused pass: compact band [sl, sh) into LDS  +  S_lo =
    //      sum_{p < sl} p * (-log p)  (select-to-1 trick, log(1)=0) ----
    int C = 0;
    float slo = 0.0f;
    #pragma unroll
    for (int k = 0; k < KPT; ++k) {
        const float pv = p[k];
        const bool below = (pv < sl);
        const float t = below ? pv : 1.0f;
        slo -= t * __logf(t);                  // += t * (-log t)
        const bool band = !below && (pv < sh);
        const unsigned long long mk = __ballot(band);
        if (band) {
            const unsigned mlo = (unsigned)mk, mhi = (unsigned)(mk >> 32);
            const int within = __builtin_amdgcn_mbcnt_hi(
                                   mhi, __builtin_amdgcn_mbcnt_lo(mlo, 0));
            const int pos = C + within;
            if (pos < CAP) scomp[wid * CAP + pos] = pv;
        }
        C += (int)__popcll(mk);
    }
    const float S_lo = dppSum(slo);
    __builtin_amdgcn_s_waitcnt(0);             // drain ds_writes (same wave)
    float cp[8];
    bool  cv[8];
    #pragma unroll
    for (int q = 0; q < 8; ++q) {
        const int idx = q * 64 + lane;
        cv[q] = (idx < C) && (idx < CAP);
        cp[q] = cv[q] ? scomp[wid * CAP + idx] : 0.0f;
    }

    float pstar, mb = 0.0f;
    int   cnt = 1;
    bool  haveTie;

    if (C > CAP) {
        // fallback (rare): keep everything >= sl (off by boundary elems only)
        pstar = (sl > 0.0f) ? __uint_as_float(__float_as_uint(sl) - 1u) : 0.0f;
        haveTie = false;
    } else {
        // ---- C1: cheap fine probes on the compact set ----
        float lo_s = sl, hi_s = sh, lo_G = Gl, hi_G = Gh;
        int   lo_C = Cl, hi_C = Ch;
        for (int it = 0; it < 10 && (lo_C - hi_C) > 2; ++it) {
            float s;
            if (it & 1) {
                s = 0.5f * (lo_s + hi_s);
            } else {
                const float den = fmaxf(lo_G - hi_G, 1e-30f);
                s = lo_s + (hi_s - lo_s) * ((lo_G - target) / den);
            }
            if (!(s > lo_s && s < hi_s)) s = 0.5f * (lo_s + hi_s);
            if (!(s > lo_s && s < hi_s)) break;

            float m = 0.0f;
            int   c = Ch;
            #pragma unroll
            for (int q = 0; q < 8; ++q) {
                const bool ge = cv[q] && (cp[q] >= s);
                m += ge ? cp[q] : 0.0f;
                c += (int)__popcll(__ballot(ge));
            }
            m = Gh + dppSum(m);
            if (m >= target) { lo_s = s; lo_G = m; lo_C = c; }
            else             { hi_s = s; hi_G = m; hi_C = c; }
        }

        // ---- C2: exact distinct-value walk downward from hi_s ----
        float scur = hi_s, M = hi_G;
        bool ok = false;
        pstar = lo_s;
        for (int e = 0; e < 16; ++e) {
            float vl = 0.0f;
            #pragma unroll
            for (int q = 0; q < 8; ++q)
                vl = fmaxf(vl, (cv[q] && cp[q] < scur) ? cp[q] : 0.0f);
            const float v = dppMax(vl);
            if (!(v > 0.0f)) break;            // fp knife-edge; fallback
            int cvn = 0;
            #pragma unroll
            for (int q = 0; q < 8; ++q)
                cvn += (int)__popcll(__ballot(cv[q] && (cp[q] == v)));
            const float Mn = M + v * (float)cvn;  // exact: ties bit-identical
            if (Mn >= target) { pstar = v; mb = M; cnt = cvn; ok = true; break; }
            M = Mn; scur = v;
        }
        haveTie = ok;
        if (!ok) {
            pstar = (lo_s > 0.0f) ? __uint_as_float(__float_as_uint(lo_s) - 1u)
                                  : 0.0f;
        }
    }

    // ---- S_band_le = sum_{band, p <= p*} p * (-log p)  (8 logs) ----
    float sble = 0.0f;
    #pragma unroll
    for (int q = 0; q < 8; ++q) {
        const float t = (cv[q] && (cp[q] <= pstar)) ? cp[q] : 1.0f;
        sble -= t * __logf(t);
    }
    const float S_band_le = dppSum(sble);

    // spd over {p > p*} by complement (spd_all uses exact d from setup)
    const float spd = spd_all - S_lo - S_band_le;

    if (lane == 0) {
        float tie = 0.0f;
        if (haveTie) {
            const float R = (target - mb) / pstar;      // exclusive-csum rule
            int q = (int)ceilf(R);
            if (q < 1) q = 1;
            if (q > cnt) q = cnt;
            tie = (float)q * pstar * (-__logf(pstar));
        }
        wacc[wid] = (spd + tie) / Z;
    }
    __syncthreads();                     // all waves reach exactly once
    if (tid == 0) {
        atomicAdd(out, wacc[0] + wacc[1] + wacc[2] + wacc[3]);
    }
}

extern "C" void kernel_launch(void* const* d_in, const int* in_sizes, int n_in,
                              void* d_out, int out_size, void* d_ws, size_t ws_size,
                              hipStream_t stream) {
    const float* x = (const float*)d_in[0];   // [B, N, 3]
    const float* y = (const float*)d_in[1];   // [B, M, 3]
    float* out = (float*)d_out;               // scalar

    const int nrows = in_sizes[0] / 3;        // B * N
    const int nblocks = nrows / WPB;

    hipMemsetAsync(out, 0, sizeof(float), stream);   // capture-legal stream op
    apml_row_wave<<<nblocks, WPB * 64, 0, stream>>>(x, y, out);
}